// Round 1
// baseline (939.982 us; speedup 1.0000x reference)
//
#include <hip/hip_runtime.h>

#define HW 16384      // 128*128
#define CIN 256
#define NCOMP 64
#define MASKC 100     // 4*25
#define NB 4

// ---------------- conv 1x1: x(4,256,128,128) -> feat(4,64,128,128) ----------
__global__ __launch_bounds__(256) void conv1x1_k(const float* __restrict__ x,
    const float* __restrict__ W1, const float* __restrict__ b1,
    float* __restrict__ feat) {
  __shared__ float wlds[CIN * NCOMP];   // transposed: [ci][co]
  for (int idx = threadIdx.x; idx < CIN * NCOMP; idx += 256) {
    int co = idx & 63, ci = idx >> 6;
    wlds[ci * 64 + co] = W1[co * CIN + ci];
  }
  __syncthreads();
  int gid = blockIdx.x * 256 + threadIdx.x;     // over NB*HW = 65536
  int b = gid >> 14, p = gid & (HW - 1);
  const float* xb = x + (size_t)b * CIN * HW + p;
  float acc[NCOMP];
  #pragma unroll
  for (int co = 0; co < NCOMP; co++) acc[co] = b1[co];
  for (int ci = 0; ci < CIN; ci++) {
    float xv = xb[(size_t)ci * HW];
    const float4* wrow = (const float4*)&wlds[ci * 64];
    #pragma unroll
    for (int q = 0; q < 16; q++) {
      float4 wv = wrow[q];
      acc[q * 4 + 0] += wv.x * xv;
      acc[q * 4 + 1] += wv.y * xv;
      acc[q * 4 + 2] += wv.z * xv;
      acc[q * 4 + 3] += wv.w * xv;
    }
  }
  float* fb = feat + (size_t)b * NCOMP * HW + p;
  #pragma unroll
  for (int co = 0; co < NCOMP; co++) fb[(size_t)co * HW] = acc[co];
}

// -------- conv 3x3 pad 1: feat(4,64,128,128) -> mask(4,100,128,128) ---------
__global__ __launch_bounds__(256) void conv3x3_k(const float* __restrict__ feat,
    const float* __restrict__ W2, const float* __restrict__ b2,
    float* __restrict__ mask) {
  int p = blockIdx.x * 256 + threadIdx.x;  // 0..16383
  int co = blockIdx.y, b = blockIdx.z;
  int h = p >> 7, w = p & 127;
  const float* fb = feat + (size_t)b * NCOMP * HW + p;
  const float* wc = W2 + co * NCOMP * 9;
  float acc = b2[co];
  int ym = (h > 0), yp = (h < 127), xm = (w > 0), xq = (w < 127);
  for (int ci = 0; ci < NCOMP; ci++) {
    const float* fc = fb + (size_t)ci * HW;
    const float* wk = wc + ci * 9;
    if (ym) {
      if (xm) acc += fc[-129] * wk[0];
              acc += fc[-128] * wk[1];
      if (xq) acc += fc[-127] * wk[2];
    }
    if (xm)   acc += fc[-1]   * wk[3];
              acc += fc[0]    * wk[4];
    if (xq)   acc += fc[1]    * wk[5];
    if (yp) {
      if (xm) acc += fc[127]  * wk[6];
              acc += fc[128]  * wk[7];
      if (xq) acc += fc[129]  * wk[8];
    }
  }
  mask[(((size_t)b * MASKC + co) << 14) + p] = acc;
}

// ---- pixel-shuffle + softmax(25) + 5x5 combine (collapsed to 3x3 in x) -----
__global__ __launch_bounds__(256) void combine_k(const float* __restrict__ x,
    const float* __restrict__ mask, float* __restrict__ out) {
  int gid = blockIdx.x * 256 + threadIdx.x;   // over (b,h,w) = 65536
  int b = gid >> 14, p = gid & (HW - 1);
  int h = p >> 7, w = p & 127;
  int c0 = blockIdx.y * 64;                   // channel chunk
  const float* mb = mask + (((size_t)b * MASKC) << 14) + p;

  float wagg[4][9];
  #pragma unroll
  for (int r = 0; r < 4; r++)
    #pragma unroll
    for (int k = 0; k < 9; k++) wagg[r][k] = 0.f;

  #pragma unroll
  for (int r = 0; r < 4; r++) {               // r = r1*2 + r2
    float m[25], mx = -1e30f;
    #pragma unroll
    for (int kk = 0; kk < 25; kk++) {
      m[kk] = mb[(size_t)(kk * 4 + r) << 14];
      mx = fmaxf(mx, m[kk]);
    }
    float s = 0.f;
    #pragma unroll
    for (int kk = 0; kk < 25; kk++) { m[kk] = __expf(m[kk] - mx); s += m[kk]; }
    float inv = 1.f / s;
    int r1 = r >> 1, r2 = r & 1;
    #pragma unroll
    for (int i = 0; i < 5; i++)
      #pragma unroll
      for (int j = 0; j < 5; j++) {
        int dy = (r1 + i - 2) >> 1;           // compile-time constants
        int dx = (r2 + j - 2) >> 1;
        wagg[r][(dy + 1) * 3 + (dx + 1)] += m[i * 5 + j] * inv;
      }
  }

  // zero weights whose source x-cell is out of bounds (matches zero padding)
  #pragma unroll
  for (int dy = -1; dy <= 1; dy++) {
    bool vy = (unsigned)(h + dy) < 128u;
    #pragma unroll
    for (int dx = -1; dx <= 1; dx++) {
      bool vx = (unsigned)(w + dx) < 128u;
      if (!(vy && vx)) {
        #pragma unroll
        for (int r = 0; r < 4; r++) wagg[r][(dy + 1) * 3 + dx + 1] = 0.f;
      }
    }
  }

  int ys[3] = {max(h - 1, 0), h, min(h + 1, 127)};
  int xs[3] = {max(w - 1, 0), w, min(w + 1, 127)};
  const float* xb = x + (((size_t)b * CIN + c0) << 14);
  float* ob = out + (((size_t)b * CIN + c0) << 16) + ((2 * h) << 8) + 2 * w;

  for (int c = 0; c < 64; c++) {
    const float* xc = xb + ((size_t)c << 14);
    float v[9];
    #pragma unroll
    for (int yy = 0; yy < 3; yy++)
      #pragma unroll
      for (int xx = 0; xx < 3; xx++)
        v[yy * 3 + xx] = xc[ys[yy] * 128 + xs[xx]];
    float* oc = ob + ((size_t)c << 16);
    #pragma unroll
    for (int r1 = 0; r1 < 2; r1++) {
      float a0 = 0.f, a1 = 0.f;
      #pragma unroll
      for (int k = 0; k < 9; k++) {
        a0 += wagg[r1 * 2 + 0][k] * v[k];
        a1 += wagg[r1 * 2 + 1][k] * v[k];
      }
      float2 res; res.x = a0; res.y = a1;
      *(float2*)(oc + r1 * 256) = res;
    }
  }
}

extern "C" void kernel_launch(void* const* d_in, const int* in_sizes, int n_in,
                              void* d_out, int out_size, void* d_ws, size_t ws_size,
                              hipStream_t stream) {
  const float* x  = (const float*)d_in[0];
  const float* W1 = (const float*)d_in[1];
  const float* b1 = (const float*)d_in[2];
  const float* W2 = (const float*)d_in[3];
  const float* b2 = (const float*)d_in[4];
  float* out  = (float*)d_out;
  float* feat = (float*)d_ws;                       // 4*64*16384 floats
  float* mask = feat + (size_t)NB * NCOMP * HW;     // 4*100*16384 floats

  conv1x1_k<<<256, 256, 0, stream>>>(x, W1, b1, feat);
  conv3x3_k<<<dim3(64, MASKC, NB), 256, 0, stream>>>(feat, W2, b2, mask);
  combine_k<<<dim3(256, NB), 256, 0, stream>>>(x, mask, out);
}

// Round 2
// 197.969 us; speedup vs baseline: 4.7481x; 4.7481x over previous
//
#include <hip/hip_runtime.h>

#define HW 16384      // 128*128
#define CIN 256
#define NCOMP 64
#define MASKC 100     // 4*25
#define NB 4
#define COPAD 112     // 100 padded to 7*16
#define KSTEPS 18     // 576 / 32

typedef __attribute__((ext_vector_type(8))) short bf16x8;
typedef __attribute__((ext_vector_type(4))) float f32x4;

__device__ inline ushort f2bf(float f) {
  uint x = __float_as_uint(f);
  return (ushort)((x + 0x7fffu + ((x >> 16) & 1u)) >> 16);
}

// -------- conv 1x1: x(4,256,128,128) -> feat_t(4,16384,64) bf16 -------------
__global__ __launch_bounds__(256) void conv1x1_k(const float* __restrict__ x,
    const float* __restrict__ W1, const float* __restrict__ b1,
    ushort* __restrict__ feat_t) {
  __shared__ float wlds[CIN * NCOMP];   // transposed: [ci][co]
  for (int idx = threadIdx.x; idx < CIN * NCOMP; idx += 256) {
    int co = idx & 63, ci = idx >> 6;
    wlds[ci * 64 + co] = W1[co * CIN + ci];
  }
  __syncthreads();
  int gid = blockIdx.x * 256 + threadIdx.x;     // over NB*HW = 65536
  int b = gid >> 14, p = gid & (HW - 1);
  const float* xb = x + (size_t)b * CIN * HW + p;
  float acc[NCOMP];
  #pragma unroll
  for (int co = 0; co < NCOMP; co++) acc[co] = b1[co];
  for (int ci = 0; ci < CIN; ci++) {
    float xv = xb[(size_t)ci * HW];
    const float4* wrow = (const float4*)&wlds[ci * 64];
    #pragma unroll
    for (int q = 0; q < 16; q++) {
      float4 wv = wrow[q];
      acc[q * 4 + 0] += wv.x * xv;
      acc[q * 4 + 1] += wv.y * xv;
      acc[q * 4 + 2] += wv.z * xv;
      acc[q * 4 + 3] += wv.w * xv;
    }
  }
  uint ob[32];
  #pragma unroll
  for (int q = 0; q < 32; q++)
    ob[q] = (uint)f2bf(acc[2 * q]) | ((uint)f2bf(acc[2 * q + 1]) << 16);
  uint4* dst = (uint4*)(feat_t + ((size_t)gid << 6));
  #pragma unroll
  for (int q = 0; q < 8; q++) {
    uint4 v; v.x = ob[q*4]; v.y = ob[q*4+1]; v.z = ob[q*4+2]; v.w = ob[q*4+3];
    dst[q] = v;
  }
}

// -------- weight reorder: W2(100,64,3,3) -> Wr(112, 18, 32) bf16 ------------
// K order: K = k*64 + ci  (k = 3x3 tap index, major); step s: k=s>>1, ci0=(s&1)*32
__global__ __launch_bounds__(256) void wprep_k(const float* __restrict__ W2,
    ushort* __restrict__ Wr) {
  int i = blockIdx.x * 256 + threadIdx.x;   // 112*576 = 64512
  if (i >= COPAD * 576) return;
  int co = i / 576, kk = i % 576;
  int s = kk >> 5, cip = kk & 31;
  int k = s >> 1, ci0 = (s & 1) * 32;
  float v = (co < MASKC) ? W2[(co * 64 + ci0 + cip) * 9 + k] : 0.f;
  Wr[i] = f2bf(v);
}

// -------- conv 3x3 pad 1 via MFMA: feat_t -> mask(4,100,128,128) fp32 -------
__global__ __launch_bounds__(256) void conv3x3_mfma(const ushort* __restrict__ feat_t,
    const ushort* __restrict__ Wr, const float* __restrict__ b2,
    float* __restrict__ mask) {
  __shared__ ushort lds[3 * 130 * 64];      // [row3][col130][ci64], XOR-swizzled
  __shared__ float b2s[COPAD];
  int tid = threadIdx.x;
  int bid = blockIdx.x;
  int b = bid >> 7, h = bid & 127;
  int wave = tid >> 6, lane = tid & 63;
  int l15 = lane & 15, l4 = lane >> 4;

  if (tid < COPAD) b2s[tid] = (tid < MASKC) ? b2[tid] : 0.f;

  // stage 3 feat rows (h-1,h,h+1), 128 cols + zero edge cols, swizzled
  #pragma unroll
  for (int r = 0; r < 3; r++) {
    int hh = h - 1 + r;
    bool valid = (hh >= 0) && (hh < 128);
    const uint4* src = (const uint4*)(feat_t + (((size_t)(b * 128 + hh)) << 13));
    #pragma unroll
    for (int it = 0; it < 4; it++) {
      int c = tid + it * 256;               // 0..1023
      int w = c >> 3, g = c & 7;
      int col = w + 1;
      uint dst = (uint)(((r * 130 + col) << 7) + g * 16) ^ (uint)((col & 7) << 4);
      uint4 v = {0, 0, 0, 0};
      if (valid) v = src[w * 8 + g];
      *(uint4*)((char*)lds + dst) = v;
    }
  }
  // zero edge columns (col 0 and col 129)
  if (tid < 48) {
    int r = tid >> 4, g = tid & 7, col = ((tid >> 3) & 1) ? 129 : 0;
    uint dst = (uint)(((r * 130 + col) << 7) + g * 16) ^ (uint)((col & 7) << 4);
    uint4 z = {0, 0, 0, 0};
    *(uint4*)((char*)lds + dst) = z;
  }
  __syncthreads();

  f32x4 acc[7][2];
  #pragma unroll
  for (int mt = 0; mt < 7; mt++)
    #pragma unroll
    for (int nf = 0; nf < 2; nf++) acc[mt][nf] = (f32x4){0.f, 0.f, 0.f, 0.f};

  int cb = wave * 32;                       // wave's pixel-column base

  #pragma unroll
  for (int s = 0; s < KSTEPS; s++) {
    const int k = s >> 1;                   // tap 0..8
    const int r = k / 3;                    // row offset 0..2
    const int dxi = k % 3;                  // col offset 0..2 (actual dx-1+1)
    const int ci0 = (s & 1) * 32;

    bf16x8 bfrag[2];
    #pragma unroll
    for (int nf = 0; nf < 2; nf++) {
      int col = cb + nf * 16 + l15 + dxi;   // 0..129
      uint addr = (uint)(((r * 130 + col) << 7) + ci0 * 2 + l4 * 16)
                ^ (uint)((col & 7) << 4);
      bfrag[nf] = *(const bf16x8*)((const char*)lds + addr);
    }
    bf16x8 afrag[7];
    #pragma unroll
    for (int mt = 0; mt < 7; mt++) {
      int row = mt * 16 + l15;
      afrag[mt] = *(const bf16x8*)(Wr + row * 576 + s * 32 + l4 * 8);
    }
    #pragma unroll
    for (int mt = 0; mt < 7; mt++)
      #pragma unroll
      for (int nf = 0; nf < 2; nf++)
        acc[mt][nf] = __builtin_amdgcn_mfma_f32_16x16x32_bf16(
            afrag[mt], bfrag[nf], acc[mt][nf], 0, 0, 0);
  }

  // epilogue: C/D layout col=lane&15, row=(lane>>4)*4+q
  int pixb = h * 128 + cb + l15;
  #pragma unroll
  for (int mt = 0; mt < 7; mt++) {
    #pragma unroll
    for (int nf = 0; nf < 2; nf++) {
      #pragma unroll
      for (int q = 0; q < 4; q++) {
        int co = mt * 16 + l4 * 4 + q;
        if (co < MASKC) {
          mask[(((size_t)(b * MASKC + co)) << 14) + pixb + nf * 16] =
              acc[mt][nf][q] + b2s[co];
        }
      }
    }
  }
}

// ---- pixel-shuffle + softmax(25) + 5x5 combine (collapsed to 3x3 in x) -----
__global__ __launch_bounds__(256) void combine_k(const float* __restrict__ x,
    const float* __restrict__ mask, float* __restrict__ out) {
  int gid = blockIdx.x * 256 + threadIdx.x;   // over (b,h,w) = 65536
  int b = gid >> 14, p = gid & (HW - 1);
  int h = p >> 7, w = p & 127;
  int c0 = blockIdx.y * 64;                   // channel chunk
  const float* mb = mask + (((size_t)b * MASKC) << 14) + p;

  float wagg[4][9];
  #pragma unroll
  for (int r = 0; r < 4; r++)
    #pragma unroll
    for (int k = 0; k < 9; k++) wagg[r][k] = 0.f;

  #pragma unroll
  for (int r = 0; r < 4; r++) {               // r = r1*2 + r2
    float m[25], mx = -1e30f;
    #pragma unroll
    for (int kk = 0; kk < 25; kk++) {
      m[kk] = mb[(size_t)(kk * 4 + r) << 14];
      mx = fmaxf(mx, m[kk]);
    }
    float s = 0.f;
    #pragma unroll
    for (int kk = 0; kk < 25; kk++) { m[kk] = __expf(m[kk] - mx); s += m[kk]; }
    float inv = 1.f / s;
    int r1 = r >> 1, r2 = r & 1;
    #pragma unroll
    for (int i = 0; i < 5; i++)
      #pragma unroll
      for (int j = 0; j < 5; j++) {
        int dy = (r1 + i - 2) >> 1;           // compile-time constants
        int dx = (r2 + j - 2) >> 1;
        wagg[r][(dy + 1) * 3 + (dx + 1)] += m[i * 5 + j] * inv;
      }
  }

  // zero weights whose source x-cell is out of bounds (matches zero padding)
  #pragma unroll
  for (int dy = -1; dy <= 1; dy++) {
    bool vy = (unsigned)(h + dy) < 128u;
    #pragma unroll
    for (int dx = -1; dx <= 1; dx++) {
      bool vx = (unsigned)(w + dx) < 128u;
      if (!(vy && vx)) {
        #pragma unroll
        for (int r = 0; r < 4; r++) wagg[r][(dy + 1) * 3 + dx + 1] = 0.f;
      }
    }
  }

  int ys[3] = {max(h - 1, 0), h, min(h + 1, 127)};
  int xs[3] = {max(w - 1, 0), w, min(w + 1, 127)};
  const float* xb = x + (((size_t)b * CIN + c0) << 14);
  float* ob = out + (((size_t)b * CIN + c0) << 16) + ((2 * h) << 8) + 2 * w;

  for (int c = 0; c < 64; c++) {
    const float* xc = xb + ((size_t)c << 14);
    float v[9];
    #pragma unroll
    for (int yy = 0; yy < 3; yy++)
      #pragma unroll
      for (int xx = 0; xx < 3; xx++)
        v[yy * 3 + xx] = xc[ys[yy] * 128 + xs[xx]];
    float* oc = ob + ((size_t)c << 16);
    #pragma unroll
    for (int r1 = 0; r1 < 2; r1++) {
      float a0 = 0.f, a1 = 0.f;
      #pragma unroll
      for (int k = 0; k < 9; k++) {
        a0 += wagg[r1 * 2 + 0][k] * v[k];
        a1 += wagg[r1 * 2 + 1][k] * v[k];
      }
      float2 res; res.x = a0; res.y = a1;
      *(float2*)(oc + r1 * 256) = res;
    }
  }
}

extern "C" void kernel_launch(void* const* d_in, const int* in_sizes, int n_in,
                              void* d_out, int out_size, void* d_ws, size_t ws_size,
                              hipStream_t stream) {
  const float* x  = (const float*)d_in[0];
  const float* W1 = (const float*)d_in[1];
  const float* b1 = (const float*)d_in[2];
  const float* W2 = (const float*)d_in[3];
  const float* b2 = (const float*)d_in[4];
  float* out  = (float*)d_out;

  char* ws = (char*)d_ws;
  ushort* feat_t = (ushort*)ws;                              // 8,388,608 B
  float*  mask   = (float*)(ws + 8388608);                   // 26,214,400 B
  ushort* Wr     = (ushort*)(ws + 8388608 + 26214400);       // 129,024 B

  conv1x1_k<<<256, 256, 0, stream>>>(x, W1, b1, feat_t);
  wprep_k<<<252, 256, 0, stream>>>(W2, Wr);
  conv3x3_mfma<<<NB * 128, 256, 0, stream>>>(feat_t, Wr, b2, mask);
  combine_k<<<dim3(256, NB), 256, 0, stream>>>(x, mask, out);
}

// Round 3
// 186.789 us; speedup vs baseline: 5.0323x; 1.0599x over previous
//
#include <hip/hip_runtime.h>

#define HW 16384      // 128*128
#define CIN 256
#define NCOMP 64
#define MASKC 100     // 4*25
#define NB 4
#define COPAD 112     // 100 padded to 7*16
#define KSTEPS 18     // 576 / 32

typedef __attribute__((ext_vector_type(8))) short bf16x8;
typedef __attribute__((ext_vector_type(4))) float f32x4;

__device__ inline ushort f2bf(float f) {
  uint x = __float_as_uint(f);
  return (ushort)((x + 0x7fffu + ((x >> 16) & 1u)) >> 16);
}

// -------- conv 1x1: x(4,256,128,128) -> feat_t(4,16384,64) bf16 -------------
__global__ __launch_bounds__(256) void conv1x1_k(const float* __restrict__ x,
    const float* __restrict__ W1, const float* __restrict__ b1,
    ushort* __restrict__ feat_t) {
  __shared__ float wlds[CIN * NCOMP];   // transposed: [ci][co]
  for (int idx = threadIdx.x; idx < CIN * NCOMP; idx += 256) {
    int co = idx & 63, ci = idx >> 6;
    wlds[ci * 64 + co] = W1[co * CIN + ci];
  }
  __syncthreads();
  int gid = blockIdx.x * 256 + threadIdx.x;     // over NB*HW = 65536
  int b = gid >> 14, p = gid & (HW - 1);
  const float* xb = x + (size_t)b * CIN * HW + p;
  float acc[NCOMP];
  #pragma unroll
  for (int co = 0; co < NCOMP; co++) acc[co] = b1[co];
  for (int ci = 0; ci < CIN; ci++) {
    float xv = xb[(size_t)ci * HW];
    const float4* wrow = (const float4*)&wlds[ci * 64];
    #pragma unroll
    for (int q = 0; q < 16; q++) {
      float4 wv = wrow[q];
      acc[q * 4 + 0] += wv.x * xv;
      acc[q * 4 + 1] += wv.y * xv;
      acc[q * 4 + 2] += wv.z * xv;
      acc[q * 4 + 3] += wv.w * xv;
    }
  }
  uint ob[32];
  #pragma unroll
  for (int q = 0; q < 32; q++)
    ob[q] = (uint)f2bf(acc[2 * q]) | ((uint)f2bf(acc[2 * q + 1]) << 16);
  uint4* dst = (uint4*)(feat_t + ((size_t)gid << 6));
  #pragma unroll
  for (int q = 0; q < 8; q++) {
    uint4 v; v.x = ob[q*4]; v.y = ob[q*4+1]; v.z = ob[q*4+2]; v.w = ob[q*4+3];
    dst[q] = v;
  }
}

// -------- weight reorder: W2(100,64,3,3) -> Wr(112, 18, 32) bf16 ------------
// K order: K = k*64 + ci  (k = 3x3 tap index, major); step s: k=s>>1, ci0=(s&1)*32
__global__ __launch_bounds__(256) void wprep_k(const float* __restrict__ W2,
    ushort* __restrict__ Wr) {
  int i = blockIdx.x * 256 + threadIdx.x;   // 112*576 = 64512
  if (i >= COPAD * 576) return;
  int co = i / 576, kk = i % 576;
  int s = kk >> 5, cip = kk & 31;
  int k = s >> 1, ci0 = (s & 1) * 32;
  float v = (co < MASKC) ? W2[(co * 64 + ci0 + cip) * 9 + k] : 0.f;
  Wr[i] = f2bf(v);
}

// ---- conv 3x3 pad 1 via MFMA, fused softmax + 25->9 tap aggregation --------
// Writes wagg(4,16384,4,9) fp32: per pixel, per subpixel r, 9 aggregated
// 3x3 weights (OOB-zeroed).
__global__ __launch_bounds__(256) void conv3x3_mfma(const ushort* __restrict__ feat_t,
    const ushort* __restrict__ Wr, const float* __restrict__ b2,
    float* __restrict__ wagg) {
  __shared__ __align__(16) char smem[100 * 129 * 4];   // 51,600 B (union)
  __shared__ float b2s[COPAD];
  int tid = threadIdx.x;
  int bid = blockIdx.x;
  int b = bid >> 7, h = bid & 127;
  int wave = tid >> 6, lane = tid & 63;
  int l15 = lane & 15, l4 = lane >> 4;

  if (tid < COPAD) b2s[tid] = (tid < MASKC) ? b2[tid] : 0.f;

  // stage 3 feat rows (h-1,h,h+1) as [row3][col130][ci64] bf16, XOR-swizzled
  #pragma unroll
  for (int r = 0; r < 3; r++) {
    int hh = h - 1 + r;
    bool valid = (hh >= 0) && (hh < 128);
    const uint4* src = (const uint4*)(feat_t + (((size_t)(b * 128 + hh)) << 13));
    #pragma unroll
    for (int it = 0; it < 4; it++) {
      int c = tid + it * 256;               // 0..1023
      int w = c >> 3, g = c & 7;
      int col = w + 1;
      uint dst = (uint)(((r * 130 + col) << 7) + g * 16) ^ (uint)((col & 7) << 4);
      uint4 v = {0, 0, 0, 0};
      if (valid) v = src[w * 8 + g];
      *(uint4*)(smem + dst) = v;
    }
  }
  // zero edge columns (col 0 and col 129)
  if (tid < 48) {
    int r = tid >> 4, g = tid & 7, col = ((tid >> 3) & 1) ? 129 : 0;
    uint dst = (uint)(((r * 130 + col) << 7) + g * 16) ^ (uint)((col & 7) << 4);
    uint4 z = {0, 0, 0, 0};
    *(uint4*)(smem + dst) = z;
  }
  __syncthreads();

  f32x4 acc[7][2];
  #pragma unroll
  for (int mt = 0; mt < 7; mt++)
    #pragma unroll
    for (int nf = 0; nf < 2; nf++) acc[mt][nf] = (f32x4){0.f, 0.f, 0.f, 0.f};

  int cb = wave * 32;                       // wave's pixel-column base

  #pragma unroll
  for (int s = 0; s < KSTEPS; s++) {
    const int k = s >> 1;                   // tap 0..8
    const int r = k / 3;                    // row offset 0..2
    const int dxi = k % 3;                  // col offset 0..2
    const int ci0 = (s & 1) * 32;

    bf16x8 bfrag[2];
    #pragma unroll
    for (int nf = 0; nf < 2; nf++) {
      int col = cb + nf * 16 + l15 + dxi;   // 0..129
      uint addr = (uint)(((r * 130 + col) << 7) + ci0 * 2 + l4 * 16)
                ^ (uint)((col & 7) << 4);
      bfrag[nf] = *(const bf16x8*)(smem + addr);
    }
    bf16x8 afrag[7];
    #pragma unroll
    for (int mt = 0; mt < 7; mt++) {
      int row = mt * 16 + l15;
      afrag[mt] = *(const bf16x8*)(Wr + row * 576 + s * 32 + l4 * 8);
    }
    #pragma unroll
    for (int mt = 0; mt < 7; mt++)
      #pragma unroll
      for (int nf = 0; nf < 2; nf++)
        acc[mt][nf] = __builtin_amdgcn_mfma_f32_16x16x32_bf16(
            afrag[mt], bfrag[nf], acc[mt][nf], 0, 0, 0);
  }

  // all waves done reading feat tile before we overwrite the LDS
  __syncthreads();

  // dump mask tile [co<100][129 pad] fp32 into LDS
  // C/D layout: col(pixel)=lane&15, row(co)=(lane>>4)*4+q
  float* ldsM = (float*)smem;
  #pragma unroll
  for (int mt = 0; mt < 7; mt++)
    #pragma unroll
    for (int nf = 0; nf < 2; nf++)
      #pragma unroll
      for (int q = 0; q < 4; q++) {
        int co = mt * 16 + l4 * 4 + q;
        if (co < MASKC)
          ldsM[co * 129 + cb + nf * 16 + l15] = acc[mt][nf][q] + b2s[co];
      }
  __syncthreads();

  // per-pixel softmax(25) + aggregate to 3x3 (one thread per pixel column)
  if (tid < 128) {
    int w = tid;                            // pixel col
    float wr[36];
    #pragma unroll
    for (int i = 0; i < 36; i++) wr[i] = 0.f;

    #pragma unroll
    for (int r = 0; r < 4; r++) {           // r = r1*2 + r2
      float m[25], mx = -1e30f;
      #pragma unroll
      for (int kk = 0; kk < 25; kk++) {
        m[kk] = ldsM[(kk * 4 + r) * 129 + w];
        mx = fmaxf(mx, m[kk]);
      }
      float s = 0.f;
      #pragma unroll
      for (int kk = 0; kk < 25; kk++) { m[kk] = __expf(m[kk] - mx); s += m[kk]; }
      float inv = 1.f / s;
      const int r1 = r >> 1, r2 = r & 1;
      #pragma unroll
      for (int i = 0; i < 5; i++)
        #pragma unroll
        for (int j = 0; j < 5; j++) {
          const int dy = (r1 + i - 2) >> 1;           // compile-time
          const int dx = (r2 + j - 2) >> 1;
          wr[r * 9 + (dy + 1) * 3 + (dx + 1)] += m[i * 5 + j] * inv;
        }
    }

    // zero weights whose source x-cell is out of bounds (matches zero pad)
    #pragma unroll
    for (int dy = -1; dy <= 1; dy++) {
      bool vy = (unsigned)(h + dy) < 128u;
      #pragma unroll
      for (int dx = -1; dx <= 1; dx++) {
        bool vx = (unsigned)(w + dx) < 128u;
        if (!(vy && vx)) {
          #pragma unroll
          for (int r = 0; r < 4; r++) wr[r * 9 + (dy + 1) * 3 + dx + 1] = 0.f;
        }
      }
    }

    float4* dst = (float4*)(wagg + ((size_t)((b << 14) + h * 128 + w)) * 36);
    #pragma unroll
    for (int q = 0; q < 9; q++) {
      float4 v;
      v.x = wr[q * 4 + 0]; v.y = wr[q * 4 + 1];
      v.z = wr[q * 4 + 2]; v.w = wr[q * 4 + 3];
      dst[q] = v;
    }
  }
}

// ---- combine: out[b,c,2h+r1,2w+r2] = sum_9 wagg[r][k] * x[b,c,h+dy,w+dx] ---
__global__ __launch_bounds__(256) void combine_k(const float* __restrict__ x,
    const float* __restrict__ wagg, float* __restrict__ out) {
  int gid = blockIdx.x * 256 + threadIdx.x;   // over (b,h,w) = 65536
  int b = gid >> 14, p = gid & (HW - 1);
  int h = p >> 7, w = p & 127;
  int c0 = blockIdx.y * 64;                   // channel chunk

  float wa[36];
  const float4* wv = (const float4*)(wagg + (size_t)gid * 36);
  #pragma unroll
  for (int q = 0; q < 9; q++) {
    float4 v = wv[q];
    wa[q * 4 + 0] = v.x; wa[q * 4 + 1] = v.y;
    wa[q * 4 + 2] = v.z; wa[q * 4 + 3] = v.w;
  }

  int ys[3] = {max(h - 1, 0), h, min(h + 1, 127)};
  int xs[3] = {max(w - 1, 0), w, min(w + 1, 127)};
  const float* xb = x + (((size_t)b * CIN + c0) << 14);
  float* ob = out + (((size_t)b * CIN + c0) << 16) + ((2 * h) << 8) + 2 * w;

  for (int c = 0; c < 64; c++) {
    const float* xc = xb + ((size_t)c << 14);
    float v[9];
    #pragma unroll
    for (int yy = 0; yy < 3; yy++)
      #pragma unroll
      for (int xx = 0; xx < 3; xx++)
        v[yy * 3 + xx] = xc[ys[yy] * 128 + xs[xx]];
    float* oc = ob + ((size_t)c << 16);
    #pragma unroll
    for (int r1 = 0; r1 < 2; r1++) {
      float a0 = 0.f, a1 = 0.f;
      #pragma unroll
      for (int k = 0; k < 9; k++) {
        a0 += wa[(r1 * 2 + 0) * 9 + k] * v[k];
        a1 += wa[(r1 * 2 + 1) * 9 + k] * v[k];
      }
      float2 res; res.x = a0; res.y = a1;
      *(float2*)(oc + r1 * 256) = res;
    }
  }
}

extern "C" void kernel_launch(void* const* d_in, const int* in_sizes, int n_in,
                              void* d_out, int out_size, void* d_ws, size_t ws_size,
                              hipStream_t stream) {
  const float* x  = (const float*)d_in[0];
  const float* W1 = (const float*)d_in[1];
  const float* b1 = (const float*)d_in[2];
  const float* W2 = (const float*)d_in[3];
  const float* b2 = (const float*)d_in[4];
  float* out  = (float*)d_out;

  char* ws = (char*)d_ws;
  ushort* feat_t = (ushort*)ws;                        // 8,388,608 B
  float*  wagg   = (float*)(ws + 8388608);             // 9,437,184 B
  ushort* Wr     = (ushort*)(ws + 8388608 + 9437184);  // 129,024 B

  conv1x1_k<<<256, 256, 0, stream>>>(x, W1, b1, feat_t);
  wprep_k<<<252, 256, 0, stream>>>(W2, Wr);
  conv3x3_mfma<<<NB * 128, 256, 0, stream>>>(feat_t, Wr, b2, wagg);
  combine_k<<<dim3(256, NB), 256, 0, stream>>>(x, wagg, out);
}

// Round 4
// 170.071 us; speedup vs baseline: 5.5270x; 1.0983x over previous
//
#include <hip/hip_runtime.h>

#define HW 16384      // 128*128
#define CIN 256
#define NCOMP 64
#define MASKC 100     // 4*25
#define NB 4
#define COPAD 112     // 100 padded to 7*16
#define KSTEPS 18     // 576 / 32

typedef __attribute__((ext_vector_type(8))) short bf16x8;
typedef __attribute__((ext_vector_type(4))) float f32x4;
typedef __attribute__((ext_vector_type(4), aligned(4))) float f4u;  // 4B-aligned float4

__device__ inline ushort f2bf(float f) {
  uint x = __float_as_uint(f);
  return (ushort)((x + 0x7fffu + ((x >> 16) & 1u)) >> 16);
}

// swizzle for conv1x1 LDS: p bits -> byte bits [6:3] (keeps 8B alignment)
__device__ inline uint SWZ(int p) {
  return (uint)(((p & 3) << 5) | (((p >> 2) & 3) << 3));
}

// ---- conv1x1 via MFMA: x(4,256,128,128) fp32 -> feat_t(4,16384,64) bf16 ----
// K=512: k=2*ci -> hi(x), k=2*ci+1 -> lo(x);  W1b2[co][k] = bf16(W1[co][k>>1])
__global__ __launch_bounds__(256) void conv1x1_mfma(const float* __restrict__ x,
    const ushort* __restrict__ W1b2, const float* __restrict__ b1,
    ushort* __restrict__ feat_t) {
  __shared__ __align__(16) char smem[64 * 1024];   // [64 px][512 k] bf16, swizzled
  int tid = threadIdx.x, bid = blockIdx.x;
  int b = bid >> 8, h = (bid >> 1) & 127, half = bid & 1;
  int p0 = half * 64;
  int wave = tid >> 6, lane = tid & 63;
  int l15 = lane & 15, l4 = lane >> 4;

  // stage: thread -> pixel group g (4 px), ci block of 16
  {
    int g = tid & 15, cib = (tid >> 4) * 16;
    const float* xb = x + (((size_t)b * CIN) << 14) + h * 128 + p0 + g * 4;
    #pragma unroll
    for (int it = 0; it < 16; it++) {
      int ci = cib + it;
      float4 v = *(const float4*)(xb + ((size_t)ci << 14));
      const float* vp = (const float*)&v;
      #pragma unroll
      for (int j = 0; j < 4; j++) {
        int p = g * 4 + j;
        float val = vp[j];
        ushort hi = f2bf(val);
        float hf = __uint_as_float(((uint)hi) << 16);
        ushort lo = f2bf(val - hf);
        uint pk = (uint)hi | ((uint)lo << 16);
        uint addr = (uint)((p << 10) + (ci << 2)) ^ SWZ(p);
        *(uint*)(smem + addr) = pk;
      }
    }
  }
  __syncthreads();

  f32x4 acc[4];
  #pragma unroll
  for (int mt = 0; mt < 4; mt++) acc[mt] = (f32x4){0.f, 0.f, 0.f, 0.f};

  int p = wave * 16 + l15;                  // local pixel col (this wave's nf)

  #pragma unroll
  for (int s = 0; s < 16; s++) {
    int k0 = s * 32 + l4 * 8;               // K index
    uint base = (uint)((p << 10) + (k0 << 1));
    uint a0 = base ^ SWZ(p);
    uint a1 = (base + 8) ^ SWZ(p);
    union { bf16x8 v; uint u[4]; } bf;
    uint2 lo2 = *(const uint2*)(smem + a0);
    uint2 hi2 = *(const uint2*)(smem + a1);
    bf.u[0] = lo2.x; bf.u[1] = lo2.y; bf.u[2] = hi2.x; bf.u[3] = hi2.y;
    #pragma unroll
    for (int mt = 0; mt < 4; mt++) {
      bf16x8 af = *(const bf16x8*)(W1b2 + (mt * 16 + l15) * 512 + k0);
      acc[mt] = __builtin_amdgcn_mfma_f32_16x16x32_bf16(af, bf.v, acc[mt], 0, 0, 0);
    }
  }

  // epilogue: C col(pixel)=l15, row(co)=l4*4+q ; store 4 bf16 = 8B per (mt)
  int pg = p0 + p;
  ushort* fb = feat_t + ((size_t)((b << 14) + h * 128 + pg)) * 64;
  #pragma unroll
  for (int mt = 0; mt < 4; mt++) {
    float4 bv = *(const float4*)(b1 + mt * 16 + l4 * 4);
    const float* bvp = (const float*)&bv;
    uint u0 = (uint)f2bf(acc[mt][0] + bvp[0]) | ((uint)f2bf(acc[mt][1] + bvp[1]) << 16);
    uint u1 = (uint)f2bf(acc[mt][2] + bvp[2]) | ((uint)f2bf(acc[mt][3] + bvp[3]) << 16);
    uint2 st; st.x = u0; st.y = u1;
    *(uint2*)(fb + mt * 16 + l4 * 4) = st;
  }
}

// ---- weight prep: Wr(112,18,32) bf16  +  W1b2(64,512) bf16 -----------------
__global__ __launch_bounds__(256) void wprep_k(const float* __restrict__ W2,
    const float* __restrict__ W1, ushort* __restrict__ Wr,
    ushort* __restrict__ W1b2) {
  int i = blockIdx.x * 256 + threadIdx.x;
  if (i < COPAD * 576) {
    int co = i / 576, kk = i % 576;
    int s = kk >> 5, cip = kk & 31;
    int k = s >> 1, ci0 = (s & 1) * 32;
    float v = (co < MASKC) ? W2[(co * 64 + ci0 + cip) * 9 + k] : 0.f;
    Wr[i] = f2bf(v);
  } else if (i < COPAD * 576 + 64 * 512) {
    int j = i - COPAD * 576;
    int co = j >> 9, k = j & 511;
    W1b2[j] = f2bf(W1[co * 256 + (k >> 1)]);
  }
}

// ---- conv 3x3 pad 1 via MFMA, fused softmax + 25->9 tap aggregation --------
__global__ __launch_bounds__(256) void conv3x3_mfma(const ushort* __restrict__ feat_t,
    const ushort* __restrict__ Wr, const float* __restrict__ b2,
    float* __restrict__ wagg) {
  __shared__ __align__(16) char smem[100 * 129 * 4];   // 51,600 B (union)
  __shared__ float b2s[COPAD];
  int tid = threadIdx.x;
  int bid = blockIdx.x;
  int b = bid >> 7, h = bid & 127;
  int wave = tid >> 6, lane = tid & 63;
  int l15 = lane & 15, l4 = lane >> 4;

  if (tid < COPAD) b2s[tid] = (tid < MASKC) ? b2[tid] : 0.f;

  #pragma unroll
  for (int r = 0; r < 3; r++) {
    int hh = h - 1 + r;
    bool valid = (hh >= 0) && (hh < 128);
    const uint4* src = (const uint4*)(feat_t + (((size_t)(b * 128 + hh)) << 13));
    #pragma unroll
    for (int it = 0; it < 4; it++) {
      int c = tid + it * 256;
      int w = c >> 3, g = c & 7;
      int col = w + 1;
      uint dst = (uint)(((r * 130 + col) << 7) + g * 16) ^ (uint)((col & 7) << 4);
      uint4 v = {0, 0, 0, 0};
      if (valid) v = src[w * 8 + g];
      *(uint4*)(smem + dst) = v;
    }
  }
  if (tid < 48) {
    int r = tid >> 4, g = tid & 7, col = ((tid >> 3) & 1) ? 129 : 0;
    uint dst = (uint)(((r * 130 + col) << 7) + g * 16) ^ (uint)((col & 7) << 4);
    uint4 z = {0, 0, 0, 0};
    *(uint4*)(smem + dst) = z;
  }
  __syncthreads();

  f32x4 acc[7][2];
  #pragma unroll
  for (int mt = 0; mt < 7; mt++)
    #pragma unroll
    for (int nf = 0; nf < 2; nf++) acc[mt][nf] = (f32x4){0.f, 0.f, 0.f, 0.f};

  int cb = wave * 32;

  #pragma unroll
  for (int s = 0; s < KSTEPS; s++) {
    const int k = s >> 1;
    const int r = k / 3;
    const int dxi = k % 3;
    const int ci0 = (s & 1) * 32;

    bf16x8 bfrag[2];
    #pragma unroll
    for (int nf = 0; nf < 2; nf++) {
      int col = cb + nf * 16 + l15 + dxi;
      uint addr = (uint)(((r * 130 + col) << 7) + ci0 * 2 + l4 * 16)
                ^ (uint)((col & 7) << 4);
      bfrag[nf] = *(const bf16x8*)(smem + addr);
    }
    bf16x8 afrag[7];
    #pragma unroll
    for (int mt = 0; mt < 7; mt++) {
      int row = mt * 16 + l15;
      afrag[mt] = *(const bf16x8*)(Wr + row * 576 + s * 32 + l4 * 8);
    }
    #pragma unroll
    for (int mt = 0; mt < 7; mt++)
      #pragma unroll
      for (int nf = 0; nf < 2; nf++)
        acc[mt][nf] = __builtin_amdgcn_mfma_f32_16x16x32_bf16(
            afrag[mt], bfrag[nf], acc[mt][nf], 0, 0, 0);
  }

  __syncthreads();

  float* ldsM = (float*)smem;
  #pragma unroll
  for (int mt = 0; mt < 7; mt++)
    #pragma unroll
    for (int nf = 0; nf < 2; nf++)
      #pragma unroll
      for (int q = 0; q < 4; q++) {
        int co = mt * 16 + l4 * 4 + q;
        if (co < MASKC)
          ldsM[co * 129 + cb + nf * 16 + l15] = acc[mt][nf][q] + b2s[co];
      }
  __syncthreads();

  if (tid < 128) {
    int w = tid;
    float wr[36];
    #pragma unroll
    for (int i = 0; i < 36; i++) wr[i] = 0.f;

    #pragma unroll
    for (int r = 0; r < 4; r++) {
      float m[25], mx = -1e30f;
      #pragma unroll
      for (int kk = 0; kk < 25; kk++) {
        m[kk] = ldsM[(kk * 4 + r) * 129 + w];
        mx = fmaxf(mx, m[kk]);
      }
      float s = 0.f;
      #pragma unroll
      for (int kk = 0; kk < 25; kk++) { m[kk] = __expf(m[kk] - mx); s += m[kk]; }
      float inv = 1.f / s;
      const int r1 = r >> 1, r2 = r & 1;
      #pragma unroll
      for (int i = 0; i < 5; i++)
        #pragma unroll
        for (int j = 0; j < 5; j++) {
          const int dy = (r1 + i - 2) >> 1;
          const int dx = (r2 + j - 2) >> 1;
          wr[r * 9 + (dy + 1) * 3 + (dx + 1)] += m[i * 5 + j] * inv;
        }
    }

    #pragma unroll
    for (int dy = -1; dy <= 1; dy++) {
      bool vy = (unsigned)(h + dy) < 128u;
      #pragma unroll
      for (int dx = -1; dx <= 1; dx++) {
        bool vx = (unsigned)(w + dx) < 128u;
        if (!(vy && vx)) {
          #pragma unroll
          for (int r = 0; r < 4; r++) wr[r * 9 + (dy + 1) * 3 + dx + 1] = 0.f;
        }
      }
    }

    float4* dst = (float4*)(wagg + ((size_t)((b << 14) + h * 128 + w)) * 36);
    #pragma unroll
    for (int q = 0; q < 9; q++) {
      float4 v;
      v.x = wr[q * 4 + 0]; v.y = wr[q * 4 + 1];
      v.z = wr[q * 4 + 2]; v.w = wr[q * 4 + 3];
      dst[q] = v;
    }
  }
}

// ---- combine v2: pixel-pair threads, float4 x-window, float4 stores --------
__global__ __launch_bounds__(256) void combine_k(const float* __restrict__ x,
    const float* __restrict__ wagg, float* __restrict__ out) {
  int gid = blockIdx.x * 256 + threadIdx.x;   // 32768: (b, h, wp)
  int b = gid >> 13, hwp = gid & 8191;
  int h = hwp >> 6, wp = hwp & 63;
  int w0 = wp * 2;
  int c0 = blockIdx.y * 64;

  int sh = (w0 == 0) ? -1 : ((w0 == 126) ? 1 : 0);
  int cc0 = w0 - 1 - sh;                      // x col load base, in [0,124]

  // load 72 aggregated weights (pixA then pixB, each [4r][9])
  float a36[36], b36[36];
  {
    const float4* wv = (const float4*)(wagg + ((size_t)(b << 14) + h * 128 + w0) * 36);
    #pragma unroll
    for (int q = 0; q < 9; q++) {
      float4 v = wv[q];
      a36[q * 4 + 0] = v.x; a36[q * 4 + 1] = v.y;
      a36[q * 4 + 2] = v.z; a36[q * 4 + 3] = v.w;
    }
    #pragma unroll
    for (int q = 0; q < 9; q++) {
      float4 v = wv[9 + q];
      b36[q * 4 + 0] = v.x; b36[q * 4 + 1] = v.y;
      b36[q * 4 + 2] = v.z; b36[q * 4 + 3] = v.w;
    }
  }

  // one-time branchless permute: weight for f4 element i (x col cc0+i)
  bool s0 = (sh == 0), sm = (sh == -1);
  float wAp[4][3][4], wBp[4][3][4];
  #pragma unroll
  for (int r = 0; r < 4; r++)
    #pragma unroll
    for (int dy = 0; dy < 3; dy++)
      #pragma unroll
      for (int i = 0; i < 4; i++) {
        // A-pixel: pa = i - sh  (weight col w0-1+pa)
        float v0 = (i <= 2) ? a36[r * 9 + dy * 3 + i] : 0.f;          // sh=0
        float vm = (i + 1 <= 2) ? a36[r * 9 + dy * 3 + i + 1] : 0.f;  // sh=-1
        float vp = (i >= 1) ? a36[r * 9 + dy * 3 + i - 1] : 0.f;      // sh=+1
        wAp[r][dy][i] = s0 ? v0 : (sm ? vm : vp);
        // B-pixel: pb = i - 1 - sh (weight col w0+pb)
        float u0 = (i >= 1) ? b36[r * 9 + dy * 3 + i - 1] : 0.f;
        float um = (i <= 2) ? b36[r * 9 + dy * 3 + i] : 0.f;
        float up = (i >= 2) ? b36[r * 9 + dy * 3 + i - 2] : 0.f;
        wBp[r][dy][i] = s0 ? u0 : (sm ? um : up);
      }

  int ys[3] = {max(h - 1, 0), h, min(h + 1, 127)};
  const float* xb = x + (((size_t)(b * CIN + c0)) << 14);
  float* ob = out + (((size_t)(b * CIN + c0)) << 16) + ((2 * h) << 8) + 4 * wp;

  #pragma unroll 4
  for (int c = 0; c < 64; c++) {
    const float* xc = xb + ((size_t)c << 14);
    float aA0 = 0.f, aA1 = 0.f, aA2 = 0.f, aA3 = 0.f;
    float aB0 = 0.f, aB1 = 0.f, aB2 = 0.f, aB3 = 0.f;
    #pragma unroll
    for (int dy = 0; dy < 3; dy++) {
      f4u f = *(const f4u*)(xc + ys[dy] * 128 + cc0);
      aA0 += wAp[0][dy][0]*f[0] + wAp[0][dy][1]*f[1] + wAp[0][dy][2]*f[2] + wAp[0][dy][3]*f[3];
      aA1 += wAp[1][dy][0]*f[0] + wAp[1][dy][1]*f[1] + wAp[1][dy][2]*f[2] + wAp[1][dy][3]*f[3];
      aA2 += wAp[2][dy][0]*f[0] + wAp[2][dy][1]*f[1] + wAp[2][dy][2]*f[2] + wAp[2][dy][3]*f[3];
      aA3 += wAp[3][dy][0]*f[0] + wAp[3][dy][1]*f[1] + wAp[3][dy][2]*f[2] + wAp[3][dy][3]*f[3];
      aB0 += wBp[0][dy][0]*f[0] + wBp[0][dy][1]*f[1] + wBp[0][dy][2]*f[2] + wBp[0][dy][3]*f[3];
      aB1 += wBp[1][dy][0]*f[0] + wBp[1][dy][1]*f[1] + wBp[1][dy][2]*f[2] + wBp[1][dy][3]*f[3];
      aB2 += wBp[2][dy][0]*f[0] + wBp[2][dy][1]*f[1] + wBp[2][dy][2]*f[2] + wBp[2][dy][3]*f[3];
      aB3 += wBp[3][dy][0]*f[0] + wBp[3][dy][1]*f[1] + wBp[3][dy][2]*f[2] + wBp[3][dy][3]*f[3];
    }
    float* oc = ob + ((size_t)c << 16);
    float4 o0; o0.x = aA0; o0.y = aA1; o0.z = aB0; o0.w = aB1;
    float4 o1; o1.x = aA2; o1.y = aA3; o1.z = aB2; o1.w = aB3;
    *(float4*)(oc) = o0;
    *(float4*)(oc + 256) = o1;
  }
}

extern "C" void kernel_launch(void* const* d_in, const int* in_sizes, int n_in,
                              void* d_out, int out_size, void* d_ws, size_t ws_size,
                              hipStream_t stream) {
  const float* x  = (const float*)d_in[0];
  const float* W1 = (const float*)d_in[1];
  const float* b1 = (const float*)d_in[2];
  const float* W2 = (const float*)d_in[3];
  const float* b2 = (const float*)d_in[4];
  float* out  = (float*)d_out;

  char* ws = (char*)d_ws;
  ushort* feat_t = (ushort*)ws;                                   // 8,388,608 B
  float*  wagg   = (float*)(ws + 8388608);                        // 9,437,184 B
  ushort* Wr     = (ushort*)(ws + 8388608 + 9437184);             // 129,024 B
  ushort* W1b2   = (ushort*)(ws + 8388608 + 9437184 + 129024);    // 65,536 B

  wprep_k<<<380, 256, 0, stream>>>(W2, W1, Wr, W1b2);
  conv1x1_mfma<<<NB * 128 * 2, 256, 0, stream>>>(x, W1b2, b1, feat_t);
  conv3x3_mfma<<<NB * 128, 256, 0, stream>>>(feat_t, Wr, b2, wagg);
  combine_k<<<dim3(128, NB), 256, 0, stream>>>(x, wagg, out);
}

// Round 5
// 140.106 us; speedup vs baseline: 6.7091x; 1.2139x over previous
//
#include <hip/hip_runtime.h>

#define HW 16384      // 128*128
#define CIN 256
#define NCOMP 64
#define MASKC 100     // 4*25
#define NB 4
#define COPAD 112     // 100 padded to 7*16
#define KSTEPS 18     // 576 / 32

typedef __attribute__((ext_vector_type(8))) short bf16x8;
typedef __attribute__((ext_vector_type(4))) float f32x4;

__device__ inline ushort f2bf(float f) {
  uint x = __float_as_uint(f);
  return (ushort)((x + 0x7fffu + ((x >> 16) & 1u)) >> 16);
}

// ---- conv1x1 via MFMA, LDS-free: x(4,256,128,128) fp32 -> feat_t(4,16384,64) bf16
// B-frag: lane(l15)=pixel col, k = s*32 + l4*8 + j  (j contiguous in register)
__global__ __launch_bounds__(256) void conv1x1_mfma(const float* __restrict__ x,
    const ushort* __restrict__ W1b, const float* __restrict__ b1,
    ushort* __restrict__ feat_t) {
  int tid = threadIdx.x, bid = blockIdx.x;    // 1024 blocks
  int b = bid >> 8, h = (bid >> 1) & 127, half = bid & 1;
  int p0 = half * 64;
  int wave = tid >> 6, lane = tid & 63;
  int l15 = lane & 15, l4 = lane >> 4;
  int px = p0 + wave * 16 + l15;              // col in row h

  const float* xb = x + ((size_t)b << 22) + h * 128 + px;

  f32x4 acc[4];
  #pragma unroll
  for (int mt = 0; mt < 4; mt++) acc[mt] = (f32x4){0.f, 0.f, 0.f, 0.f};

  #pragma unroll
  for (int s = 0; s < 8; s++) {
    int k0 = s * 32 + l4 * 8;
    union { bf16x8 v; ushort u[8]; } bf;
    #pragma unroll
    for (int j = 0; j < 8; j++)
      bf.u[j] = f2bf(xb[(size_t)(k0 + j) << 14]);
    #pragma unroll
    for (int mt = 0; mt < 4; mt++) {
      bf16x8 af = *(const bf16x8*)(W1b + (mt * 16 + l15) * 256 + k0);
      acc[mt] = __builtin_amdgcn_mfma_f32_16x16x32_bf16(af, bf.v, acc[mt], 0, 0, 0);
    }
  }

  // epilogue: C col(pixel)=l15, row(co)=l4*4+q
  ushort* fb = feat_t + ((size_t)((b << 14) + h * 128 + px)) * 64;
  #pragma unroll
  for (int mt = 0; mt < 4; mt++) {
    float4 bv = *(const float4*)(b1 + mt * 16 + l4 * 4);
    const float* bvp = (const float*)&bv;
    uint u0 = (uint)f2bf(acc[mt][0] + bvp[0]) | ((uint)f2bf(acc[mt][1] + bvp[1]) << 16);
    uint u1 = (uint)f2bf(acc[mt][2] + bvp[2]) | ((uint)f2bf(acc[mt][3] + bvp[3]) << 16);
    uint2 st; st.x = u0; st.y = u1;
    *(uint2*)(fb + mt * 16 + l4 * 4) = st;
  }
}

// ---- weight prep: Wr(112,18,32) bf16  +  W1b(64,256) bf16 ------------------
__global__ __launch_bounds__(256) void wprep_k(const float* __restrict__ W2,
    const float* __restrict__ W1, ushort* __restrict__ Wr,
    ushort* __restrict__ W1b) {
  int i = blockIdx.x * 256 + threadIdx.x;
  if (i < COPAD * 576) {
    int co = i / 576, kk = i % 576;
    int s = kk >> 5, cip = kk & 31;
    int k = s >> 1, ci0 = (s & 1) * 32;
    float v = (co < MASKC) ? W2[(co * 64 + ci0 + cip) * 9 + k] : 0.f;
    Wr[i] = f2bf(v);
  } else if (i < COPAD * 576 + 64 * 256) {
    int j = i - COPAD * 576;
    W1b[j] = f2bf(W1[j]);
  }
}

// ---- conv 3x3 pad 1 via MFMA, fused softmax + 25->9 tap aggregation --------
__global__ __launch_bounds__(256) void conv3x3_mfma(const ushort* __restrict__ feat_t,
    const ushort* __restrict__ Wr, const float* __restrict__ b2,
    float* __restrict__ wagg) {
  __shared__ __align__(16) char smem[100 * 129 * 4];   // 51,600 B (union)
  __shared__ float b2s[COPAD];
  int tid = threadIdx.x;
  int bid = blockIdx.x;
  int b = bid >> 7, h = bid & 127;
  int wave = tid >> 6, lane = tid & 63;
  int l15 = lane & 15, l4 = lane >> 4;

  if (tid < COPAD) b2s[tid] = (tid < MASKC) ? b2[tid] : 0.f;

  #pragma unroll
  for (int r = 0; r < 3; r++) {
    int hh = h - 1 + r;
    bool valid = (hh >= 0) && (hh < 128);
    const uint4* src = (const uint4*)(feat_t + (((size_t)(b * 128 + hh)) << 13));
    #pragma unroll
    for (int it = 0; it < 4; it++) {
      int c = tid + it * 256;
      int w = c >> 3, g = c & 7;
      int col = w + 1;
      uint dst = (uint)(((r * 130 + col) << 7) + g * 16) ^ (uint)((col & 7) << 4);
      uint4 v = {0, 0, 0, 0};
      if (valid) v = src[w * 8 + g];
      *(uint4*)(smem + dst) = v;
    }
  }
  if (tid < 48) {
    int r = tid >> 4, g = tid & 7, col = ((tid >> 3) & 1) ? 129 : 0;
    uint dst = (uint)(((r * 130 + col) << 7) + g * 16) ^ (uint)((col & 7) << 4);
    uint4 z = {0, 0, 0, 0};
    *(uint4*)(smem + dst) = z;
  }
  __syncthreads();

  f32x4 acc[7][2];
  #pragma unroll
  for (int mt = 0; mt < 7; mt++)
    #pragma unroll
    for (int nf = 0; nf < 2; nf++) acc[mt][nf] = (f32x4){0.f, 0.f, 0.f, 0.f};

  int cb = wave * 32;

  #pragma unroll
  for (int s = 0; s < KSTEPS; s++) {
    const int k = s >> 1;
    const int r = k / 3;
    const int dxi = k % 3;
    const int ci0 = (s & 1) * 32;

    bf16x8 bfrag[2];
    #pragma unroll
    for (int nf = 0; nf < 2; nf++) {
      int col = cb + nf * 16 + l15 + dxi;
      uint addr = (uint)(((r * 130 + col) << 7) + ci0 * 2 + l4 * 16)
                ^ (uint)((col & 7) << 4);
      bfrag[nf] = *(const bf16x8*)(smem + addr);
    }
    bf16x8 afrag[7];
    #pragma unroll
    for (int mt = 0; mt < 7; mt++) {
      int row = mt * 16 + l15;
      afrag[mt] = *(const bf16x8*)(Wr + row * 576 + s * 32 + l4 * 8);
    }
    #pragma unroll
    for (int mt = 0; mt < 7; mt++)
      #pragma unroll
      for (int nf = 0; nf < 2; nf++)
        acc[mt][nf] = __builtin_amdgcn_mfma_f32_16x16x32_bf16(
            afrag[mt], bfrag[nf], acc[mt][nf], 0, 0, 0);
  }

  __syncthreads();

  float* ldsM = (float*)smem;
  #pragma unroll
  for (int mt = 0; mt < 7; mt++)
    #pragma unroll
    for (int nf = 0; nf < 2; nf++)
      #pragma unroll
      for (int q = 0; q < 4; q++) {
        int co = mt * 16 + l4 * 4 + q;
        if (co < MASKC)
          ldsM[co * 129 + cb + nf * 16 + l15] = acc[mt][nf][q] + b2s[co];
      }
  __syncthreads();

  if (tid < 128) {
    int w = tid;
    float wr[36];
    #pragma unroll
    for (int i = 0; i < 36; i++) wr[i] = 0.f;

    #pragma unroll
    for (int r = 0; r < 4; r++) {
      float m[25], mx = -1e30f;
      #pragma unroll
      for (int kk = 0; kk < 25; kk++) {
        m[kk] = ldsM[(kk * 4 + r) * 129 + w];
        mx = fmaxf(mx, m[kk]);
      }
      float s = 0.f;
      #pragma unroll
      for (int kk = 0; kk < 25; kk++) { m[kk] = __expf(m[kk] - mx); s += m[kk]; }
      float inv = 1.f / s;
      const int r1 = r >> 1, r2 = r & 1;
      #pragma unroll
      for (int i = 0; i < 5; i++)
        #pragma unroll
        for (int j = 0; j < 5; j++) {
          const int dy = (r1 + i - 2) >> 1;
          const int dx = (r2 + j - 2) >> 1;
          wr[r * 9 + (dy + 1) * 3 + (dx + 1)] += m[i * 5 + j] * inv;
        }
    }

    #pragma unroll
    for (int dy = -1; dy <= 1; dy++) {
      bool vy = (unsigned)(h + dy) < 128u;
      #pragma unroll
      for (int dx = -1; dx <= 1; dx++) {
        bool vx = (unsigned)(w + dx) < 128u;
        if (!(vy && vx)) {
          #pragma unroll
          for (int r = 0; r < 4; r++) wr[r * 9 + (dy + 1) * 3 + dx + 1] = 0.f;
        }
      }
    }

    float4* dst = (float4*)(wagg + ((size_t)((b << 14) + h * 128 + w)) * 36);
    #pragma unroll
    for (int q = 0; q < 9; q++) {
      float4 v;
      v.x = wr[q * 4 + 0]; v.y = wr[q * 4 + 1];
      v.z = wr[q * 4 + 2]; v.w = wr[q * 4 + 3];
      dst[q] = v;
    }
  }
}

// ---- combine v3: one pixel/thread, 32 channels/thread, high occupancy ------
__global__ __launch_bounds__(256) void combine_k(const float* __restrict__ x,
    const float* __restrict__ wagg, float* __restrict__ out) {
  int gid = blockIdx.x * 256 + threadIdx.x;   // 65536 over (b,h,w)
  int b = gid >> 14, p = gid & (HW - 1);
  int h = p >> 7, w = p & 127;
  int c0 = blockIdx.y * 32;

  float wr[36];
  {
    const float4* wv = (const float4*)(wagg + (size_t)gid * 36);
    #pragma unroll
    for (int q = 0; q < 9; q++) {
      float4 v = wv[q];
      wr[q * 4 + 0] = v.x; wr[q * 4 + 1] = v.y;
      wr[q * 4 + 2] = v.z; wr[q * 4 + 3] = v.w;
    }
  }

  int ys[3] = {max(h - 1, 0) * 128, h * 128, min(h + 1, 127) * 128};
  int xs[3] = {max(w - 1, 0), w, min(w + 1, 127)};
  const float* xb = x + (((size_t)(b * CIN + c0)) << 14);
  float* ob = out + (((size_t)(b * CIN + c0)) << 16) + ((2 * h) << 8) + 2 * w;

  for (int c = 0; c < 32; c++) {
    const float* xc = xb + ((size_t)c << 14);
    float v[9];
    #pragma unroll
    for (int yy = 0; yy < 3; yy++)
      #pragma unroll
      for (int xx = 0; xx < 3; xx++)
        v[yy * 3 + xx] = xc[ys[yy] + xs[xx]];
    float a0 = 0.f, a1 = 0.f, a2 = 0.f, a3 = 0.f;
    #pragma unroll
    for (int k = 0; k < 9; k++) {
      a0 += wr[0 * 9 + k] * v[k];
      a1 += wr[1 * 9 + k] * v[k];
      a2 += wr[2 * 9 + k] * v[k];
      a3 += wr[3 * 9 + k] * v[k];
    }
    float* oc = ob + ((size_t)c << 16);
    float2 e0; e0.x = a0; e0.y = a1;
    float2 e1; e1.x = a2; e1.y = a3;
    *(float2*)(oc) = e0;
    *(float2*)(oc + 256) = e1;
  }
}

extern "C" void kernel_launch(void* const* d_in, const int* in_sizes, int n_in,
                              void* d_out, int out_size, void* d_ws, size_t ws_size,
                              hipStream_t stream) {
  const float* x  = (const float*)d_in[0];
  const float* W1 = (const float*)d_in[1];
  const float* b1 = (const float*)d_in[2];
  const float* W2 = (const float*)d_in[3];
  const float* b2 = (const float*)d_in[4];
  float* out  = (float*)d_out;

  char* ws = (char*)d_ws;
  ushort* feat_t = (ushort*)ws;                                   // 8,388,608 B
  float*  wagg   = (float*)(ws + 8388608);                        // 9,437,184 B
  ushort* Wr     = (ushort*)(ws + 8388608 + 9437184);             // 129,024 B
  ushort* W1b    = (ushort*)(ws + 8388608 + 9437184 + 129024);    // 32,768 B

  wprep_k<<<316, 256, 0, stream>>>(W2, W1, Wr, W1b);
  conv1x1_mfma<<<NB * 128 * 2, 256, 0, stream>>>(x, W1b, b1, feat_t);
  conv3x3_mfma<<<NB * 128, 256, 0, stream>>>(feat_t, Wr, b2, wagg);
  combine_k<<<dim3(256, 8), 256, 0, stream>>>(x, wagg, out);
}

// Round 7
// 134.865 us; speedup vs baseline: 6.9698x; 1.0389x over previous
//
#include <hip/hip_runtime.h>

#define HW 16384      // 128*128
#define CIN 256
#define NCOMP 64
#define MASKC 100     // 4*25
#define NB 4
#define COPAD 112     // 100 padded to 7*16
#define KSTEPS 18     // 576 / 32

typedef __attribute__((ext_vector_type(8))) short bf16x8;
typedef __attribute__((ext_vector_type(4))) float f32x4;

__device__ inline ushort f2bf(float f) {
  uint x = __float_as_uint(f);
  return (ushort)((x + 0x7fffu + ((x >> 16) & 1u)) >> 16);
}

// ---- conv1x1 via MFMA, 2-row blocks: x(4,256,128,128) fp32 -> feat_t(4,16384,64) bf16
// Block = (b, hp) with hp in [0,64): pixels n in [0,256) covering rows 2hp, 2hp+1.
__global__ __launch_bounds__(256) void conv1x1_mfma(const float* __restrict__ x,
    const ushort* __restrict__ W1b, const float* __restrict__ b1,
    ushort* __restrict__ feat_t) {
  int tid = threadIdx.x, bid = blockIdx.x;    // NB*64 = 256 blocks
  int b = bid >> 6, hp = bid & 63;
  int wave = tid >> 6, lane = tid & 63;
  int l15 = lane & 15, l4 = lane >> 4;

  const float* xb = x + ((size_t)b << 22) + hp * 256;

  f32x4 acc[4][4];                            // [u tile][mt]
  #pragma unroll
  for (int u = 0; u < 4; u++)
    #pragma unroll
    for (int mt = 0; mt < 4; mt++) acc[u][mt] = (f32x4){0.f, 0.f, 0.f, 0.f};

  #pragma unroll
  for (int s = 0; s < 8; s++) {
    int k0 = s * 32 + l4 * 8;                 // ci base for this lane
    bf16x8 af[4];
    #pragma unroll
    for (int mt = 0; mt < 4; mt++)
      af[mt] = *(const bf16x8*)(W1b + (mt * 16 + l15) * 256 + k0);
    #pragma unroll
    for (int u = 0; u < 4; u++) {
      int n = wave * 64 + u * 16 + l15;       // pixel within block
      union { bf16x8 v; ushort us[8]; } bf;
      #pragma unroll
      for (int j = 0; j < 8; j++)
        bf.us[j] = f2bf(xb[((size_t)(k0 + j) << 14) + n]);
      #pragma unroll
      for (int mt = 0; mt < 4; mt++)
        acc[u][mt] = __builtin_amdgcn_mfma_f32_16x16x32_bf16(af[mt], bf.v, acc[u][mt], 0, 0, 0);
    }
  }

  // epilogue: C col(pixel)=l15, row(co)=l4*4+q
  ushort* fbase = feat_t + (((size_t)(b << 14) + hp * 256) << 6);
  #pragma unroll
  for (int u = 0; u < 4; u++) {
    int n = wave * 64 + u * 16 + l15;
    ushort* fb = fbase + ((size_t)n << 6);
    #pragma unroll
    for (int mt = 0; mt < 4; mt++) {
      float4 bv = *(const float4*)(b1 + mt * 16 + l4 * 4);
      const float* bvp = (const float*)&bv;
      uint u0 = (uint)f2bf(acc[u][mt][0] + bvp[0]) | ((uint)f2bf(acc[u][mt][1] + bvp[1]) << 16);
      uint u1 = (uint)f2bf(acc[u][mt][2] + bvp[2]) | ((uint)f2bf(acc[u][mt][3] + bvp[3]) << 16);
      uint2 st; st.x = u0; st.y = u1;
      *(uint2*)(fb + mt * 16 + l4 * 4) = st;
    }
  }
}

// ---- weight prep: Wr(112,18,32) bf16  +  W1b(64,256) bf16 ------------------
__global__ __launch_bounds__(256) void wprep_k(const float* __restrict__ W2,
    const float* __restrict__ W1, ushort* __restrict__ Wr,
    ushort* __restrict__ W1b) {
  int i = blockIdx.x * 256 + threadIdx.x;
  if (i < COPAD * 576) {
    int co = i / 576, kk = i % 576;
    int s = kk >> 5, cip = kk & 31;
    int k = s >> 1, ci0 = (s & 1) * 32;
    float v = (co < MASKC) ? W2[(co * 64 + ci0 + cip) * 9 + k] : 0.f;
    Wr[i] = f2bf(v);
  } else if (i < COPAD * 576 + 64 * 256) {
    int j = i - COPAD * 576;
    W1b[j] = f2bf(W1[j]);
  }
}

// ---- FUSED: conv3x3 (MFMA) + softmax + 25->9 aggregation + combine ---------
// One block per (b, h). Writes out rows 2h, 2h+1 for all 256 channels.
__global__ __launch_bounds__(256) void conv3x3_combine(const ushort* __restrict__ feat_t,
    const ushort* __restrict__ Wr, const float* __restrict__ b2,
    const float* __restrict__ x, float* __restrict__ out) {
  __shared__ __align__(16) char smem[100 * 129 * 4];   // 51,600 B (multi-use)
  __shared__ float b2s[COPAD];
  int tid = threadIdx.x;
  int bid = blockIdx.x;
  int b = bid >> 7, h = bid & 127;
  int wave = tid >> 6, lane = tid & 63;
  int l15 = lane & 15, l4 = lane >> 4;

  if (tid < COPAD) b2s[tid] = (tid < MASKC) ? b2[tid] : 0.f;

  // ---- phase 1: stage feat rows (h-1,h,h+1) as [r][col130][ci64], swizzled
  #pragma unroll
  for (int r = 0; r < 3; r++) {
    int hh = h - 1 + r;
    bool valid = (hh >= 0) && (hh < 128);
    const uint4* src = (const uint4*)(feat_t + (((size_t)(b * 128 + hh)) << 13));
    #pragma unroll
    for (int it = 0; it < 4; it++) {
      int c = tid + it * 256;
      int w = c >> 3, g = c & 7;
      int col = w + 1;
      uint dst = (uint)(((r * 130 + col) << 7) + g * 16) ^ (uint)((col & 7) << 4);
      uint4 v = {0, 0, 0, 0};
      if (valid) v = src[w * 8 + g];
      *(uint4*)(smem + dst) = v;
    }
  }
  if (tid < 48) {
    int r = tid >> 4, g = tid & 7, col = ((tid >> 3) & 1) ? 129 : 0;
    uint dst = (uint)(((r * 130 + col) << 7) + g * 16) ^ (uint)((col & 7) << 4);
    uint4 z = {0, 0, 0, 0};
    *(uint4*)(smem + dst) = z;
  }
  __syncthreads();

  // ---- phase 2: MFMA K-loop
  f32x4 acc[7][2];
  #pragma unroll
  for (int mt = 0; mt < 7; mt++)
    #pragma unroll
    for (int nf = 0; nf < 2; nf++) acc[mt][nf] = (f32x4){0.f, 0.f, 0.f, 0.f};

  int cb = wave * 32;

  #pragma unroll
  for (int s = 0; s < KSTEPS; s++) {
    const int k = s >> 1;
    const int r = k / 3;
    const int dxi = k % 3;
    const int ci0 = (s & 1) * 32;

    bf16x8 bfrag[2];
    #pragma unroll
    for (int nf = 0; nf < 2; nf++) {
      int col = cb + nf * 16 + l15 + dxi;
      uint addr = (uint)(((r * 130 + col) << 7) + ci0 * 2 + l4 * 16)
                ^ (uint)((col & 7) << 4);
      bfrag[nf] = *(const bf16x8*)(smem + addr);
    }
    bf16x8 afrag[7];
    #pragma unroll
    for (int mt = 0; mt < 7; mt++) {
      int row = mt * 16 + l15;
      afrag[mt] = *(const bf16x8*)(Wr + row * 576 + s * 32 + l4 * 8);
    }
    #pragma unroll
    for (int mt = 0; mt < 7; mt++)
      #pragma unroll
      for (int nf = 0; nf < 2; nf++)
        acc[mt][nf] = __builtin_amdgcn_mfma_f32_16x16x32_bf16(
            afrag[mt], bfrag[nf], acc[mt][nf], 0, 0, 0);
  }

  __syncthreads();

  // ---- phase 3: dump mask tile [co<100][129] fp32 into LDS
  float* ldsM = (float*)smem;
  #pragma unroll
  for (int mt = 0; mt < 7; mt++)
    #pragma unroll
    for (int nf = 0; nf < 2; nf++)
      #pragma unroll
      for (int q = 0; q < 4; q++) {
        int co = mt * 16 + l4 * 4 + q;
        if (co < MASKC)
          ldsM[co * 129 + cb + nf * 16 + l15] = acc[mt][nf][q] + b2s[co];
      }
  __syncthreads();

  // ---- phase 4: per-pixel softmax(25) + aggregate to 3x3 (128 threads)
  float wr[36];
  if (tid < 128) {
    int w = tid;
    #pragma unroll
    for (int i = 0; i < 36; i++) wr[i] = 0.f;

    #pragma unroll
    for (int r = 0; r < 4; r++) {
      float m[25], mx = -1e30f;
      #pragma unroll
      for (int kk = 0; kk < 25; kk++) {
        m[kk] = ldsM[(kk * 4 + r) * 129 + w];
        mx = fmaxf(mx, m[kk]);
      }
      float s = 0.f;
      #pragma unroll
      for (int kk = 0; kk < 25; kk++) { m[kk] = __expf(m[kk] - mx); s += m[kk]; }
      float inv = 1.f / s;
      const int r1 = r >> 1, r2 = r & 1;
      #pragma unroll
      for (int i = 0; i < 5; i++)
        #pragma unroll
        for (int j = 0; j < 5; j++) {
          const int dy = (r1 + i - 2) >> 1;
          const int dx = (r2 + j - 2) >> 1;
          wr[r * 9 + (dy + 1) * 3 + (dx + 1)] += m[i * 5 + j] * inv;
        }
    }

    #pragma unroll
    for (int dy = -1; dy <= 1; dy++) {
      bool vy = (unsigned)(h + dy) < 128u;
      #pragma unroll
      for (int dx = -1; dx <= 1; dx++) {
        bool vx = (unsigned)(w + dx) < 128u;
        if (!(vy && vx)) {
          #pragma unroll
          for (int r = 0; r < 4; r++) wr[r * 9 + (dy + 1) * 3 + dx + 1] = 0.f;
        }
      }
    }
  }
  __syncthreads();             // all ldsM reads done before overwrite

  // ---- phase 5: publish weights to LDS (stride 37, conflict-free)
  float* wlds = (float*)smem;
  if (tid < 128) {
    #pragma unroll
    for (int i = 0; i < 36; i++) wlds[tid * 37 + i] = wr[i];
  }
  __syncthreads();

  // ---- phase 6: combine. thread = (pixel p, channel-half); 128 ch each.
  {
    int p = tid & 127, half = tid >> 7;
    float wc[36];
    #pragma unroll
    for (int i = 0; i < 36; i++) wc[i] = wlds[p * 37 + i];

    int w = p;
    int ys[3] = {max(h - 1, 0) * 128, h * 128, min(h + 1, 127) * 128};
    int xs[3] = {max(w - 1, 0), w, min(w + 1, 127)};
    const float* xb = x + ((size_t)b << 22);
    float* ob = out + (((size_t)b * CIN) << 16) + ((2 * h) << 8) + 2 * w;

    #pragma unroll 4
    for (int cc = 0; cc < 128; cc++) {
      int c = cc * 2 + half;
      const float* xc = xb + ((size_t)c << 14);
      float v[9];
      #pragma unroll
      for (int yy = 0; yy < 3; yy++)
        #pragma unroll
        for (int xx = 0; xx < 3; xx++)
          v[yy * 3 + xx] = xc[ys[yy] + xs[xx]];
      float a0 = 0.f, a1 = 0.f, a2 = 0.f, a3 = 0.f;
      #pragma unroll
      for (int k = 0; k < 9; k++) {
        a0 += wc[0 * 9 + k] * v[k];
        a1 += wc[1 * 9 + k] * v[k];
        a2 += wc[2 * 9 + k] * v[k];
        a3 += wc[3 * 9 + k] * v[k];
      }
      float* oc = ob + ((size_t)c << 16);
      float2 e0; e0.x = a0; e0.y = a1;
      float2 e1; e1.x = a2; e1.y = a3;
      *(float2*)(oc) = e0;
      *(float2*)(oc + 256) = e1;
    }
  }
}

extern "C" void kernel_launch(void* const* d_in, const int* in_sizes, int n_in,
                              void* d_out, int out_size, void* d_ws, size_t ws_size,
                              hipStream_t stream) {
  const float* x  = (const float*)d_in[0];
  const float* W1 = (const float*)d_in[1];
  const float* b1 = (const float*)d_in[2];
  const float* W2 = (const float*)d_in[3];
  const float* b2 = (const float*)d_in[4];
  float* out  = (float*)d_out;

  char* ws = (char*)d_ws;
  ushort* feat_t = (ushort*)ws;                        // 8,388,608 B
  ushort* Wr     = (ushort*)(ws + 8388608);            // 129,024 B
  ushort* W1b    = (ushort*)(ws + 8388608 + 129024);   // 32,768 B

  wprep_k<<<316, 256, 0, stream>>>(W2, W1, Wr, W1b);
  conv1x1_mfma<<<NB * 64, 256, 0, stream>>>(x, W1b, b1, feat_t);
  conv3x3_combine<<<NB * 128, 256, 0, stream>>>(feat_t, Wr, b2, x, out);
}